// Round 1
// baseline (485.723 us; speedup 1.0000x reference)
//
#include <hip/hip_runtime.h>

// ---------------------------------------------------------------------------
// MatryoshkaAttention on MI355X (gfx950), bf16 MFMA pipeline.
//
// Algebra: low-rank K/V corrections (h_hi @ F) @ P are folded into effective
// W_K / W_V columns (they're linear in x), so ONE GEMM computes Q_all/K_all/
// V_all including corrections:
//   W_K_eff[256:,   0:256] += concat_h(FK0_h @ PK0_h)   (tier0)
//   W_K_eff[1024:, 256:768] += concat_h(FK1_h @ PK1_h)  (tier1)  (same for V)
//
// Stages (all on `stream`):
//  1. x fp32 -> bf16
//  2. build small correction mats (transposed, fp32) in ws
//  3. transpose+convert W_QKV -> bf16 [N=4608][K=2048] (adds corrections),
//     W_O -> bf16 [N=2048][K=1536]
//  4. GEMM1: QKV(4096x4608) bf16 = x16 @ Wt_qkv^T   (128x128 tile MFMA)
//  5. causal flash attention per (b, head, 64-row q-tile) -> ATT bf16
//  6. GEMM2: out(4096x2048) fp32 = ATT @ Wt_o^T
// ---------------------------------------------------------------------------

typedef short bf16x8 __attribute__((ext_vector_type(8)));
typedef float floatx4 __attribute__((ext_vector_type(4)));

__device__ __forceinline__ unsigned short f2bf(float f) {
  unsigned u = __builtin_bit_cast(unsigned, f);
  u += 0x7fffu + ((u >> 16) & 1u);           // RNE
  return (unsigned short)(u >> 16);
}

// ---------------- 1. x -> bf16 ----------------
__global__ void k_cvt_x(const float* __restrict__ in, unsigned short* __restrict__ out, int n4) {
  int i = blockIdx.x * blockDim.x + threadIdx.x;
  if (i >= n4) return;
  float4 v = ((const float4*)in)[i];
  union { unsigned short u[4]; uint2 v2; } o;
  o.u[0] = f2bf(v.x); o.u[1] = f2bf(v.y); o.u[2] = f2bf(v.z); o.u[3] = f2bf(v.w);
  ((uint2*)out)[i] = o.v2;
}

// ---------------- 2. Wc^T[n][k] = sum_r F[k, h*8+r] * P[h, r, d],  n = h*64+d
__global__ void k_build_wct(const float* __restrict__ F, const float* __restrict__ P,
                            float* __restrict__ out, int hi, int fstride) {
  int idx = blockIdx.x * blockDim.x + threadIdx.x;   // grid sized exactly hi*nh*64
  int k = idx % hi;
  int n = idx / hi;
  int h = n >> 6, d = n & 63;
  float s = 0.f;
#pragma unroll
  for (int r = 0; r < 8; ++r)
    s += F[(size_t)k * fstride + h * 8 + r] * P[h * 512 + r * 64 + d];
  out[(size_t)n * hi + k] = s;
}

// ---------------- 3a. W_QKV transpose+convert with corrections ----------------
// Wt[n][k], n in [0,4608), k in [0,2048). 32x32 tiles, block (32,8).
__global__ void k_pack_qkv(const float* __restrict__ WQ, const float* __restrict__ WK,
                           const float* __restrict__ WV,
                           const float* __restrict__ cK0, const float* __restrict__ cV0,
                           const float* __restrict__ cK1, const float* __restrict__ cV1,
                           unsigned short* __restrict__ Wt) {
  __shared__ float tile[32][33];
  int k0 = blockIdx.x * 32, n0 = blockIdx.y * 32;
  int tx = threadIdx.x, ty = threadIdx.y;
  const float* src;
  int nboff;
  if (n0 < 1536)      { src = WQ; nboff = n0; }
  else if (n0 < 3072) { src = WK; nboff = n0 - 1536; }
  else                { src = WV; nboff = n0 - 3072; }
#pragma unroll
  for (int j = 0; j < 4; ++j) {
    int kk = ty + j * 8;
    tile[kk][tx] = src[(size_t)(k0 + kk) * 1536 + nboff + tx];
  }
  __syncthreads();
#pragma unroll
  for (int j = 0; j < 4; ++j) {
    int nn = ty + j * 8;
    int n = n0 + nn;
    int k = k0 + tx;
    float v = tile[tx][nn];
    if (n >= 1536) {
      int np = (n < 3072) ? (n - 1536) : (n - 3072);
      const float* cA = (n < 3072) ? cK0 : cV0;
      const float* cB = (n < 3072) ? cK1 : cV1;
      if (np < 256) {
        if (k >= 256) v += cA[(size_t)np * 1792 + (k - 256)];
      } else if (np < 768) {
        if (k >= 1024) v += cB[(size_t)(np - 256) * 1024 + (k - 1024)];
      }
    }
    Wt[(size_t)n * 2048 + k] = f2bf(v);
  }
}

// ---------------- 3b. W_O transpose+convert: Wt[n][k], n<2048, k<1536 -------
__global__ void k_pack_o(const float* __restrict__ WO, unsigned short* __restrict__ Wt) {
  __shared__ float tile[32][33];
  int k0 = blockIdx.x * 32, n0 = blockIdx.y * 32;
  int tx = threadIdx.x, ty = threadIdx.y;
#pragma unroll
  for (int j = 0; j < 4; ++j)
    tile[ty + j * 8][tx] = WO[(size_t)(k0 + ty + j * 8) * 2048 + n0 + tx];
  __syncthreads();
#pragma unroll
  for (int j = 0; j < 4; ++j) {
    int n = n0 + ty + j * 8, k = k0 + tx;
    Wt[(size_t)n * 1536 + k] = f2bf(tile[tx][ty + j * 8]);
  }
}

// ---------------- 4/6. GEMM: C[M][N] = A[M][K](bf16) * Bt[N][K](bf16)^T ------
// 128x128 block tile, 4 waves in 2x2, each wave 64x64 via 4x4 MFMA 16x16x32.
// LDS stride 40 (pad) -> 2-way-max bank aliasing (free per m136), 16B aligned.
#define LDT 40
template <bool OUT_BF16>
__global__ __launch_bounds__(256) void k_gemm_bt(const unsigned short* __restrict__ A,
                                                 const unsigned short* __restrict__ Bt,
                                                 void* __restrict__ C, int M, int N, int K) {
  __shared__ unsigned short As[128 * LDT];
  __shared__ unsigned short Bs[128 * LDT];
  const int tid = threadIdx.x;
  const int wave = tid >> 6, lane = tid & 63;
  const int qd = lane >> 4, ln = lane & 15;
  const int bm = blockIdx.y * 128, bn = blockIdx.x * 128;
  const int wr = wave >> 1, wc = wave & 1;
  floatx4 acc[4][4];
#pragma unroll
  for (int i = 0; i < 4; ++i)
#pragma unroll
    for (int j = 0; j < 4; ++j) acc[i][j] = (floatx4){0.f, 0.f, 0.f, 0.f};
  const int row_s = tid >> 2;
  const int cc_s = (tid & 3) << 3;
  for (int k0 = 0; k0 < K; k0 += 32) {
    __syncthreads();
#pragma unroll
    for (int i = 0; i < 2; ++i) {
      int row = row_s + i * 64;
      uint4 va = *(const uint4*)(A + (size_t)(bm + row) * K + k0 + cc_s);
      *(uint4*)(As + row * LDT + cc_s) = va;
      uint4 vb = *(const uint4*)(Bt + (size_t)(bn + row) * K + k0 + cc_s);
      *(uint4*)(Bs + row * LDT + cc_s) = vb;
    }
    __syncthreads();
    bf16x8 af[4], bfr[4];
#pragma unroll
    for (int mi = 0; mi < 4; ++mi)
      af[mi] = *(const bf16x8*)(As + (wr * 64 + mi * 16 + ln) * LDT + qd * 8);
#pragma unroll
    for (int ni = 0; ni < 4; ++ni)
      bfr[ni] = *(const bf16x8*)(Bs + (wc * 64 + ni * 16 + ln) * LDT + qd * 8);
#pragma unroll
    for (int mi = 0; mi < 4; ++mi)
#pragma unroll
      for (int ni = 0; ni < 4; ++ni)
        acc[mi][ni] = __builtin_amdgcn_mfma_f32_16x16x32_bf16(af[mi], bfr[ni], acc[mi][ni], 0, 0, 0);
  }
#pragma unroll
  for (int mi = 0; mi < 4; ++mi)
#pragma unroll
    for (int r = 0; r < 4; ++r) {
      int row = bm + wr * 64 + mi * 16 + qd * 4 + r;
#pragma unroll
      for (int ni = 0; ni < 4; ++ni) {
        int col = bn + wc * 64 + ni * 16 + ln;
        if (OUT_BF16)
          ((unsigned short*)C)[(size_t)row * N + col] = f2bf(acc[mi][ni][r]);
        else
          ((float*)C)[(size_t)row * N + col] = acc[mi][ni][r];
      }
    }
}

// ---------------- 5. causal flash attention ----------------
// grid (16 qtiles, 24 heads, 4 batch), block 256 (4 waves x 16 q-rows).
// QKV row-major [4096][4608]: Q cols 64*gh, K cols 1536+64*gh, V 3072+64*gh.
#define LDK 72
#define LDV 40
#define LDP 40
__global__ __launch_bounds__(256) void k_attn(const unsigned short* __restrict__ QKV,
                                              unsigned short* __restrict__ Oout) {
  __shared__ unsigned short Ks[32 * LDK];
  __shared__ unsigned short Vst[64 * LDV];   // Vst[d][key] (transposed)
  __shared__ unsigned short Pl[4][16 * LDP]; // wave-private P staging
  const int tid = threadIdx.x;
  const int wave = tid >> 6, lane = tid & 63;
  const int qd = lane >> 4, ln = lane & 15;
  const int qb = blockIdx.x, gh = blockIdx.y, b = blockIdx.z;
  const int T = 1024, LD = 4608;
  const size_t rowbase = (size_t)b * T * LD;
  const int qcol = 64 * gh, kcol = 1536 + 64 * gh, vcol = 3072 + 64 * gh;
  const int q0w = qb * 64 + wave * 16;

  bf16x8 aq0, aq1;
  {
    const unsigned short* qp = QKV + rowbase + (size_t)(q0w + ln) * LD + qcol;
    aq0 = *(const bf16x8*)(qp + qd * 8);
    aq1 = *(const bf16x8*)(qp + 32 + qd * 8);
  }
  floatx4 Oacc[4];
#pragma unroll
  for (int i = 0; i < 4; ++i) Oacc[i] = (floatx4){0.f, 0.f, 0.f, 0.f};
  float m_r[4], l_r[4];
#pragma unroll
  for (int r = 0; r < 4; ++r) { m_r[r] = -1e30f; l_r[r] = 0.f; }

  const int ntiles = 2 * qb + 2;
  for (int jt = 0; jt < ntiles; ++jt) {
    const int jk = jt * 32;
    __syncthreads();
    {
      int key = tid >> 3, c0 = (tid & 7) * 8;
      uint4 vk = *(const uint4*)(QKV + rowbase + (size_t)(jk + key) * LD + kcol + c0);
      *(uint4*)(Ks + key * LDK + c0) = vk;
      union { uint4 v; unsigned short u[8]; } vv;
      vv.v = *(const uint4*)(QKV + rowbase + (size_t)(jk + key) * LD + vcol + c0);
#pragma unroll
      for (int j = 0; j < 8; ++j) Vst[(c0 + j) * LDV + key] = vv.u[j];
    }
    __syncthreads();

    // S = Q K^T  (two 16-key halves)
    floatx4 Sc[2];
    Sc[0] = (floatx4){0.f, 0.f, 0.f, 0.f};
    Sc[1] = (floatx4){0.f, 0.f, 0.f, 0.f};
#pragma unroll
    for (int h = 0; h < 2; ++h) {
      bf16x8 b0 = *(const bf16x8*)(Ks + (h * 16 + ln) * LDK + qd * 8);
      bf16x8 b1 = *(const bf16x8*)(Ks + (h * 16 + ln) * LDK + 32 + qd * 8);
      Sc[h] = __builtin_amdgcn_mfma_f32_16x16x32_bf16(aq0, b0, Sc[h], 0, 0, 0);
      Sc[h] = __builtin_amdgcn_mfma_f32_16x16x32_bf16(aq1, b1, Sc[h], 0, 0, 0);
    }
    // scale + causal mask; row = q0w+qd*4+r, key = jk+h*16+ln
    float s[2][4];
#pragma unroll
    for (int h = 0; h < 2; ++h)
#pragma unroll
      for (int r = 0; r < 4; ++r) {
        int qrow = q0w + qd * 4 + r;
        int kidx = jk + h * 16 + ln;
        float v = Sc[h][r] * 0.125f;
        s[h][r] = (kidx <= qrow) ? v : -1e30f;
      }
    // online softmax per row (rows live in 16-lane quad groups)
#pragma unroll
    for (int r = 0; r < 4; ++r) {
      float mx = fmaxf(s[0][r], s[1][r]);
#pragma unroll
      for (int off = 1; off < 16; off <<= 1) mx = fmaxf(mx, __shfl_xor(mx, off, 64));
      float mn = fmaxf(m_r[r], mx);
      float al = __expf(m_r[r] - mn);
      float p0 = __expf(s[0][r] - mn);
      float p1 = __expf(s[1][r] - mn);
      s[0][r] = p0; s[1][r] = p1;
      float sum = p0 + p1;
#pragma unroll
      for (int off = 1; off < 16; off <<= 1) sum += __shfl_xor(sum, off, 64);
      l_r[r] = l_r[r] * al + sum;
      m_r[r] = mn;
#pragma unroll
      for (int nc = 0; nc < 4; ++nc) Oacc[nc][r] *= al;
    }
    // P (C-layout) -> LDS -> A-layout fragment (wave-private, no barrier)
    unsigned short* pw = Pl[wave];
#pragma unroll
    for (int r = 0; r < 4; ++r) {
      pw[(qd * 4 + r) * LDP + ln] = f2bf(s[0][r]);
      pw[(qd * 4 + r) * LDP + 16 + ln] = f2bf(s[1][r]);
    }
    __asm__ volatile("s_waitcnt lgkmcnt(0)" ::: "memory");
    bf16x8 pa = *(const bf16x8*)(pw + ln * LDP + qd * 8);
#pragma unroll
    for (int nc = 0; nc < 4; ++nc) {
      bf16x8 bv = *(const bf16x8*)(Vst + (nc * 16 + ln) * LDV + qd * 8);
      Oacc[nc] = __builtin_amdgcn_mfma_f32_16x16x32_bf16(pa, bv, Oacc[nc], 0, 0, 0);
    }
  }
  // epilogue: O /= l, store bf16 into ATT[4096][1536]
#pragma unroll
  for (int r = 0; r < 4; ++r) {
    float inv = 1.0f / l_r[r];
    size_t row = (size_t)b * T + q0w + qd * 4 + r;
#pragma unroll
    for (int nc = 0; nc < 4; ++nc)
      Oout[row * 1536 + 64 * gh + nc * 16 + ln] = f2bf(Oacc[nc][r] * inv);
  }
}

// ---------------------------------------------------------------------------
extern "C" void kernel_launch(void* const* d_in, const int* in_sizes, int n_in,
                              void* d_out, int out_size, void* d_ws, size_t ws_size,
                              hipStream_t stream) {
  (void)in_sizes; (void)n_in; (void)out_size; (void)ws_size;
  const float* x   = (const float*)d_in[0];
  const float* WQ  = (const float*)d_in[1];
  const float* WK  = (const float*)d_in[2];
  const float* WV  = (const float*)d_in[3];
  const float* WO  = (const float*)d_in[4];
  const float* FK0 = (const float*)d_in[5];
  const float* PK0 = (const float*)d_in[6];
  const float* FV0 = (const float*)d_in[7];
  const float* PV0 = (const float*)d_in[8];
  const float* FK1 = (const float*)d_in[9];
  const float* PK1 = (const float*)d_in[10];
  const float* FV1 = (const float*)d_in[11];
  const float* PV1 = (const float*)d_in[12];

  char* ws = (char*)d_ws;
  unsigned short* X16   = (unsigned short*)(ws + 0);          // 16 MB: x bf16 [4096][2048]
  unsigned short* WTQKV = (unsigned short*)(ws + 16777216);   // 18 MB: Wt_qkv [4608][2048]
  unsigned short* QKV   = (unsigned short*)(ws + 35651584);   // 36 MB: QKV bf16 [4096][4608]
  unsigned short* ATT   = (unsigned short*)(ws + 73400320);   // 12 MB: attn out [4096][1536]
  unsigned short* WTO   = (unsigned short*)(ws + 85983232);   //  6 MB: Wt_o [2048][1536]
  float* WCK0 = (float*)(ws + 92274688);                      // [256][1792]
  float* WCV0 = (float*)(ws + 94109696);                      // [256][1792]
  float* WCK1 = (float*)(ws + 95944704);                      // [512][1024]
  float* WCV1 = (float*)(ws + 98041856);                      // [512][1024]  end ~100.2 MB

  k_cvt_x<<<8192, 256, 0, stream>>>(x, X16, 2097152);
  k_build_wct<<<1792, 256, 0, stream>>>(FK0, PK0, WCK0, 1792, 32);
  k_build_wct<<<1792, 256, 0, stream>>>(FV0, PV0, WCV0, 1792, 32);
  k_build_wct<<<2048, 256, 0, stream>>>(FK1, PK1, WCK1, 1024, 64);
  k_build_wct<<<2048, 256, 0, stream>>>(FV1, PV1, WCV1, 1024, 64);
  k_pack_qkv<<<dim3(64, 144), dim3(32, 8), 0, stream>>>(WQ, WK, WV, WCK0, WCV0, WCK1, WCV1, WTQKV);
  k_pack_o<<<dim3(48, 64), dim3(32, 8), 0, stream>>>(WO, WTO);
  k_gemm_bt<true><<<dim3(36, 32), 256, 0, stream>>>(X16, WTQKV, QKV, 4096, 4608, 2048);
  k_attn<<<dim3(16, 24, 4), 256, 0, stream>>>(QKV, ATT);
  k_gemm_bt<false><<<dim3(16, 32), 256, 0, stream>>>(ATT, WTO, d_out, 4096, 2048, 1536);
}

// Round 2
// 418.976 us; speedup vs baseline: 1.1593x; 1.1593x over previous
//
#include <hip/hip_runtime.h>

// ---------------------------------------------------------------------------
// MatryoshkaAttention on MI355X (gfx950), bf16 MFMA pipeline. Round 2.
//
// Changes vs R1:
//  - k_attn: V is pre-transposed once into VT[b][d][T] (k_transpose_v), so
//    attention staging is pure uint4 row copies (no 16-way-conflict scalar
//    transpose). 64-key tiles (half the barriers), mask VALU only on the
//    diagonal tile, exp2-domain online softmax, reversed qb order (big
//    blocks dispatch first).
//  - k_gemm_bt: m97 structure — global_load_lds width=16 into unpadded
//    [128][32] LDS double tiles.
//  - VT buffer aliases X16's workspace region (X16 dead after GEMM1).
// ---------------------------------------------------------------------------

typedef short bf16x8 __attribute__((ext_vector_type(8)));
typedef float floatx4 __attribute__((ext_vector_type(4)));

__device__ __forceinline__ unsigned short f2bf(float f) {
  unsigned u = __builtin_bit_cast(unsigned, f);
  u += 0x7fffu + ((u >> 16) & 1u);           // RNE
  return (unsigned short)(u >> 16);
}

__device__ __forceinline__ void gload_lds16(const unsigned short* g, unsigned short* l) {
  __builtin_amdgcn_global_load_lds((const __attribute__((address_space(1))) unsigned int*)g,
                                   (__attribute__((address_space(3))) unsigned int*)l, 16, 0, 0);
}

// ---------------- 1. x -> bf16 ----------------
__global__ void k_cvt_x(const float* __restrict__ in, unsigned short* __restrict__ out, int n4) {
  int i = blockIdx.x * blockDim.x + threadIdx.x;
  if (i >= n4) return;
  float4 v = ((const float4*)in)[i];
  union { unsigned short u[4]; uint2 v2; } o;
  o.u[0] = f2bf(v.x); o.u[1] = f2bf(v.y); o.u[2] = f2bf(v.z); o.u[3] = f2bf(v.w);
  ((uint2*)out)[i] = o.v2;
}

// ---------------- 2. Wc^T[n][k] = sum_r F[k, h*8+r] * P[h, r, d],  n = h*64+d
__global__ void k_build_wct(const float* __restrict__ F, const float* __restrict__ P,
                            float* __restrict__ out, int hi, int fstride) {
  int idx = blockIdx.x * blockDim.x + threadIdx.x;
  int k = idx % hi;
  int n = idx / hi;
  int h = n >> 6, d = n & 63;
  float s = 0.f;
#pragma unroll
  for (int r = 0; r < 8; ++r)
    s += F[(size_t)k * fstride + h * 8 + r] * P[h * 512 + r * 64 + d];
  out[(size_t)n * hi + k] = s;
}

// ---------------- 3a. W_QKV transpose+convert with corrections ----------------
__global__ void k_pack_qkv(const float* __restrict__ WQ, const float* __restrict__ WK,
                           const float* __restrict__ WV,
                           const float* __restrict__ cK0, const float* __restrict__ cV0,
                           const float* __restrict__ cK1, const float* __restrict__ cV1,
                           unsigned short* __restrict__ Wt) {
  __shared__ float tile[32][33];
  int k0 = blockIdx.x * 32, n0 = blockIdx.y * 32;
  int tx = threadIdx.x, ty = threadIdx.y;
  const float* src;
  int nboff;
  if (n0 < 1536)      { src = WQ; nboff = n0; }
  else if (n0 < 3072) { src = WK; nboff = n0 - 1536; }
  else                { src = WV; nboff = n0 - 3072; }
#pragma unroll
  for (int j = 0; j < 4; ++j) {
    int kk = ty + j * 8;
    tile[kk][tx] = src[(size_t)(k0 + kk) * 1536 + nboff + tx];
  }
  __syncthreads();
#pragma unroll
  for (int j = 0; j < 4; ++j) {
    int nn = ty + j * 8;
    int n = n0 + nn;
    int k = k0 + tx;
    float v = tile[tx][nn];
    if (n >= 1536) {
      int np = (n < 3072) ? (n - 1536) : (n - 3072);
      const float* cA = (n < 3072) ? cK0 : cV0;
      const float* cB = (n < 3072) ? cK1 : cV1;
      if (np < 256) {
        if (k >= 256) v += cA[(size_t)np * 1792 + (k - 256)];
      } else if (np < 768) {
        if (k >= 1024) v += cB[(size_t)(np - 256) * 1024 + (k - 1024)];
      }
    }
    Wt[(size_t)n * 2048 + k] = f2bf(v);
  }
}

// ---------------- 3b. W_O transpose+convert: Wt[n][k], n<2048, k<1536 -------
__global__ void k_pack_o(const float* __restrict__ WO, unsigned short* __restrict__ Wt) {
  __shared__ float tile[32][33];
  int k0 = blockIdx.x * 32, n0 = blockIdx.y * 32;
  int tx = threadIdx.x, ty = threadIdx.y;
#pragma unroll
  for (int j = 0; j < 4; ++j)
    tile[ty + j * 8][tx] = WO[(size_t)(k0 + ty + j * 8) * 2048 + n0 + tx];
  __syncthreads();
#pragma unroll
  for (int j = 0; j < 4; ++j) {
    int n = n0 + ty + j * 8, k = k0 + tx;
    Wt[(size_t)n * 1536 + k] = f2bf(tile[tx][ty + j * 8]);
  }
}

// ---------------- 4/6. GEMM (m97 structure): C = A[M][K] * Bt[N][K]^T --------
// 128x128 tile, 4 waves 2x2, BK=32, global_load_lds dwordx4, unpadded LDS.
template <bool OUT_BF16>
__global__ __launch_bounds__(256) void k_gemm_bt(const unsigned short* __restrict__ A,
                                                 const unsigned short* __restrict__ Bt,
                                                 void* __restrict__ C, int M, int N, int K) {
  __shared__ unsigned short As[128 * 32];
  __shared__ unsigned short Bs[128 * 32];
  const int tid = threadIdx.x;
  const int wave = tid >> 6, lane = tid & 63;
  const int qd = lane >> 4, ln = lane & 15;
  const int bm = blockIdx.y * 128, bn = blockIdx.x * 128;
  const int wr = wave >> 1, wc = wave & 1;
  floatx4 acc[4][4];
#pragma unroll
  for (int i = 0; i < 4; ++i)
#pragma unroll
    for (int j = 0; j < 4; ++j) acc[i][j] = (floatx4){0.f, 0.f, 0.f, 0.f};
  // staging: wave w owns rows [w*32, w*32+32); one instr = 16 rows (64 lanes x 16B)
  const int srow = wave * 32 + (lane >> 2);
  const int scol = (lane & 3) * 8;
  const unsigned short* gA = A + (size_t)(bm + srow) * K + scol;
  const unsigned short* gB = Bt + (size_t)(bn + srow) * K + scol;
  unsigned short* lA = As + wave * 1024;
  unsigned short* lB = Bs + wave * 1024;
  for (int k0 = 0; k0 < K; k0 += 32) {
    __syncthreads();
    gload_lds16(gA + k0, lA);
    gload_lds16(gA + (size_t)16 * K + k0, lA + 512);
    gload_lds16(gB + k0, lB);
    gload_lds16(gB + (size_t)16 * K + k0, lB + 512);
    __syncthreads();
    bf16x8 af[4], bfr[4];
#pragma unroll
    for (int mi = 0; mi < 4; ++mi)
      af[mi] = *(const bf16x8*)(As + (wr * 64 + mi * 16 + ln) * 32 + qd * 8);
#pragma unroll
    for (int ni = 0; ni < 4; ++ni)
      bfr[ni] = *(const bf16x8*)(Bs + (wc * 64 + ni * 16 + ln) * 32 + qd * 8);
#pragma unroll
    for (int mi = 0; mi < 4; ++mi)
#pragma unroll
      for (int ni = 0; ni < 4; ++ni)
        acc[mi][ni] = __builtin_amdgcn_mfma_f32_16x16x32_bf16(af[mi], bfr[ni], acc[mi][ni], 0, 0, 0);
  }
#pragma unroll
  for (int mi = 0; mi < 4; ++mi)
#pragma unroll
    for (int r = 0; r < 4; ++r) {
      int row = bm + wr * 64 + mi * 16 + qd * 4 + r;
#pragma unroll
      for (int ni = 0; ni < 4; ++ni) {
        int col = bn + wc * 64 + ni * 16 + ln;
        if (OUT_BF16)
          ((unsigned short*)C)[(size_t)row * N + col] = f2bf(acc[mi][ni][r]);
        else
          ((float*)C)[(size_t)row * N + col] = acc[mi][ni][r];
      }
    }
}

// ---------------- 4b. V transpose: VT[b][d(1536)][T] from QKV cols 3072+ ----
// 64x64 short tiles; LDS stride 65 -> conflict-free scalar transpose.
__global__ void k_transpose_v(const unsigned short* __restrict__ QKV,
                              unsigned short* __restrict__ VT) {
  __shared__ unsigned short t[64 * 65];
  const int tt = blockIdx.x * 64, dt = blockIdx.y * 64, b = blockIdx.z;
  const int tid = threadIdx.x;
  const int r = tid >> 3, c0 = (tid & 7) * 8;
#pragma unroll
  for (int i = 0; i < 2; ++i) {
    int tok = r + i * 32;
    union { uint4 v; unsigned short u[8]; } vv;
    vv.v = *(const uint4*)(QKV + (size_t)(b * 1024 + tt + tok) * 4608 + 3072 + dt + c0);
#pragma unroll
    for (int j = 0; j < 8; ++j) t[tok * 65 + c0 + j] = vv.u[j];
  }
  __syncthreads();
#pragma unroll
  for (int i = 0; i < 2; ++i) {
    int d = r + i * 32;
    union { uint4 v; unsigned short u[8]; } vv;
#pragma unroll
    for (int j = 0; j < 8; ++j) vv.u[j] = t[(c0 + j) * 65 + d];
    *(uint4*)(VT + ((size_t)b * 1536 + dt + d) * 1024 + tt + c0) = vv.v;
  }
}

// ---------------- 5. causal flash attention (64-key tiles) ----------------
// grid (16 qtiles [reversed], 24 heads, 4 batch), block 256 = 4 waves x 16 q.
#define LDK 72   // shorts; 144B row stride, 16B aligned
#define LDP 72
__global__ __launch_bounds__(256) void k_attn(const unsigned short* __restrict__ QKV,
                                              const unsigned short* __restrict__ VT,
                                              unsigned short* __restrict__ Oout) {
  __shared__ unsigned short Ks[64 * LDK];
  __shared__ unsigned short VTs[64 * LDK];   // VTs[d][key]
  __shared__ unsigned short Pl[4][16 * LDP]; // wave-private P staging
  const int tid = threadIdx.x;
  const int wave = tid >> 6, lane = tid & 63;
  const int qd = lane >> 4, ln = lane & 15;
  const int qb = (int)gridDim.x - 1 - (int)blockIdx.x;   // big blocks first
  const int gh = blockIdx.y, b = blockIdx.z;
  const int T = 1024, LD = 4608;
  const size_t rowbase = (size_t)b * T * LD;
  const int qcol = 64 * gh, kcol = 1536 + 64 * gh;
  const int q0w = qb * 64 + wave * 16;
  const unsigned short* VTg = VT + ((size_t)b * 1536 + 64 * gh) * 1024;
  const float SCALE = 0.18033688f;  // 1/sqrt(64) * log2(e)

  bf16x8 aq0, aq1;
  {
    const unsigned short* qp = QKV + rowbase + (size_t)(q0w + ln) * LD + qcol;
    aq0 = *(const bf16x8*)(qp + qd * 8);
    aq1 = *(const bf16x8*)(qp + 32 + qd * 8);
  }
  floatx4 Oacc[4];
#pragma unroll
  for (int i = 0; i < 4; ++i) Oacc[i] = (floatx4){0.f, 0.f, 0.f, 0.f};
  float m_r[4], l_r[4];
#pragma unroll
  for (int r = 0; r < 4; ++r) { m_r[r] = -1e30f; l_r[r] = 0.f; }

  const int rr = tid >> 3, c0 = (tid & 7) * 8;
  for (int jt = 0; jt <= qb; ++jt) {
    const int jk = jt * 64;
    const bool diag = (jt == qb);
    __syncthreads();
#pragma unroll
    for (int i = 0; i < 2; ++i) {
      int kr = rr + i * 32;
      uint4 vk = *(const uint4*)(QKV + rowbase + (size_t)(jk + kr) * LD + kcol + c0);
      *(uint4*)(Ks + kr * LDK + c0) = vk;
      uint4 vv = *(const uint4*)(VTg + (size_t)kr * 1024 + jk + c0);
      *(uint4*)(VTs + kr * LDK + c0) = vv;
    }
    __syncthreads();

    // S = Q K^T : 4 fragments of 16 keys
    floatx4 Sc[4];
#pragma unroll
    for (int h = 0; h < 4; ++h) {
      Sc[h] = (floatx4){0.f, 0.f, 0.f, 0.f};
      bf16x8 b0 = *(const bf16x8*)(Ks + (h * 16 + ln) * LDK + qd * 8);
      bf16x8 b1 = *(const bf16x8*)(Ks + (h * 16 + ln) * LDK + 32 + qd * 8);
      Sc[h] = __builtin_amdgcn_mfma_f32_16x16x32_bf16(aq0, b0, Sc[h], 0, 0, 0);
      Sc[h] = __builtin_amdgcn_mfma_f32_16x16x32_bf16(aq1, b1, Sc[h], 0, 0, 0);
    }
    float s[4][4];
    if (diag) {
#pragma unroll
      for (int h = 0; h < 4; ++h)
#pragma unroll
        for (int r = 0; r < 4; ++r) {
          int qrow = q0w + qd * 4 + r;
          int kidx = jk + h * 16 + ln;
          s[h][r] = (kidx <= qrow) ? Sc[h][r] * SCALE : -1e30f;
        }
    } else {
#pragma unroll
      for (int h = 0; h < 4; ++h)
#pragma unroll
        for (int r = 0; r < 4; ++r) s[h][r] = Sc[h][r] * SCALE;
    }
    // online softmax (exp2 domain); rows live in 16-lane groups
#pragma unroll
    for (int r = 0; r < 4; ++r) {
      float mx = fmaxf(fmaxf(s[0][r], s[1][r]), fmaxf(s[2][r], s[3][r]));
#pragma unroll
      for (int off = 1; off < 16; off <<= 1) mx = fmaxf(mx, __shfl_xor(mx, off, 64));
      float mn = fmaxf(m_r[r], mx);
      float al = __builtin_amdgcn_exp2f(m_r[r] - mn);
      float sum = 0.f;
#pragma unroll
      for (int h = 0; h < 4; ++h) {
        s[h][r] = __builtin_amdgcn_exp2f(s[h][r] - mn);
        sum += s[h][r];
      }
#pragma unroll
      for (int off = 1; off < 16; off <<= 1) sum += __shfl_xor(sum, off, 64);
      l_r[r] = l_r[r] * al + sum;
      m_r[r] = mn;
#pragma unroll
      for (int nc = 0; nc < 4; ++nc) Oacc[nc][r] *= al;
    }
    // P (C-layout) -> wave-private LDS -> A-layout fragments
    unsigned short* pw = Pl[wave];
#pragma unroll
    for (int r = 0; r < 4; ++r)
#pragma unroll
      for (int h = 0; h < 4; ++h)
        pw[(qd * 4 + r) * LDP + h * 16 + ln] = f2bf(s[h][r]);
    __asm__ volatile("s_waitcnt lgkmcnt(0)" ::: "memory");
    bf16x8 pa0 = *(const bf16x8*)(pw + ln * LDP + qd * 8);
    bf16x8 pa1 = *(const bf16x8*)(pw + ln * LDP + 32 + qd * 8);
#pragma unroll
    for (int nc = 0; nc < 4; ++nc) {
      bf16x8 bv0 = *(const bf16x8*)(VTs + (nc * 16 + ln) * LDK + qd * 8);
      bf16x8 bv1 = *(const bf16x8*)(VTs + (nc * 16 + ln) * LDK + 32 + qd * 8);
      Oacc[nc] = __builtin_amdgcn_mfma_f32_16x16x32_bf16(pa0, bv0, Oacc[nc], 0, 0, 0);
      Oacc[nc] = __builtin_amdgcn_mfma_f32_16x16x32_bf16(pa1, bv1, Oacc[nc], 0, 0, 0);
    }
  }
  // epilogue
#pragma unroll
  for (int r = 0; r < 4; ++r) {
    float inv = 1.0f / l_r[r];
    size_t row = (size_t)b * T + q0w + qd * 4 + r;
#pragma unroll
    for (int nc = 0; nc < 4; ++nc)
      Oout[row * 1536 + 64 * gh + nc * 16 + ln] = f2bf(Oacc[nc][r] * inv);
  }
}

// ---------------------------------------------------------------------------
extern "C" void kernel_launch(void* const* d_in, const int* in_sizes, int n_in,
                              void* d_out, int out_size, void* d_ws, size_t ws_size,
                              hipStream_t stream) {
  (void)in_sizes; (void)n_in; (void)out_size; (void)ws_size;
  const float* x   = (const float*)d_in[0];
  const float* WQ  = (const float*)d_in[1];
  const float* WK  = (const float*)d_in[2];
  const float* WV  = (const float*)d_in[3];
  const float* WO  = (const float*)d_in[4];
  const float* FK0 = (const float*)d_in[5];
  const float* PK0 = (const float*)d_in[6];
  const float* FV0 = (const float*)d_in[7];
  const float* PV0 = (const float*)d_in[8];
  const float* FK1 = (const float*)d_in[9];
  const float* PK1 = (const float*)d_in[10];
  const float* FV1 = (const float*)d_in[11];
  const float* PV1 = (const float*)d_in[12];

  char* ws = (char*)d_ws;
  unsigned short* X16   = (unsigned short*)(ws + 0);          // 16 MB: x bf16 (dead after GEMM1)
  unsigned short* VTb   = X16;                                 // 12.6 MB: VT aliases X16
  unsigned short* WTQKV = (unsigned short*)(ws + 16777216);   // 18 MB
  unsigned short* QKV   = (unsigned short*)(ws + 35651584);   // 36 MB
  unsigned short* ATT   = (unsigned short*)(ws + 73400320);   // 12 MB
  unsigned short* WTO   = (unsigned short*)(ws + 85983232);   //  6 MB
  float* WCK0 = (float*)(ws + 92274688);
  float* WCV0 = (float*)(ws + 94109696);
  float* WCK1 = (float*)(ws + 95944704);
  float* WCV1 = (float*)(ws + 98041856);

  k_cvt_x<<<8192, 256, 0, stream>>>(x, X16, 2097152);
  k_build_wct<<<1792, 256, 0, stream>>>(FK0, PK0, WCK0, 1792, 32);
  k_build_wct<<<1792, 256, 0, stream>>>(FV0, PV0, WCV0, 1792, 32);
  k_build_wct<<<2048, 256, 0, stream>>>(FK1, PK1, WCK1, 1024, 64);
  k_build_wct<<<2048, 256, 0, stream>>>(FV1, PV1, WCV1, 1024, 64);
  k_pack_qkv<<<dim3(64, 144), dim3(32, 8), 0, stream>>>(WQ, WK, WV, WCK0, WCV0, WCK1, WCV1, WTQKV);
  k_pack_o<<<dim3(48, 64), dim3(32, 8), 0, stream>>>(WO, WTO);
  k_gemm_bt<true><<<dim3(36, 32), 256, 0, stream>>>(X16, WTQKV, QKV, 4096, 4608, 2048);
  k_transpose_v<<<dim3(16, 24, 4), 256, 0, stream>>>(QKV, VTb);
  k_attn<<<dim3(16, 24, 4), 256, 0, stream>>>(QKV, VTb, ATT);
  k_gemm_bt<false><<<dim3(16, 32), 256, 0, stream>>>(ATT, WTO, d_out, 4096, 2048, 1536);
}